// Round 1
// baseline (1490.705 us; speedup 1.0000x reference)
//
#include <hip/hip_runtime.h>
#include <math.h>

#define NN 100000
#define NE 200000
#define HD 128
#define CAPN 4096
#define CAPE 8192
#define ETILE 48
#define EPAD 132

// workspace byte offsets (all 128B aligned)
#define OFF_NCNT   0          // 21 ints
#define OFF_ECNT   256        // 21 ints
#define OFF_HSTYPE 512        // 6*128 f32
#define OFF_HSW1   3584       // 3*6*128 f32
#define OFF_WIHT   12800      // 3*128*384 f32
#define OFF_NLIST  602624     // 21*4096 ints
#define OFF_NSLOT  946688     // NN ints
#define OFF_ESRC   1346688    // 21*8192 ints
#define OFF_EDSL   2034816    // 21*8192 ints
#define OFF_MSG    2722944    // 3*4096*128 f32
#define WS_USED    9014400

__device__ __forceinline__ int gi_of(int g) {
    // GATE_CODES = (3,2,5) -> gi 0,1,2
    return (g == 3) ? 0 : (g == 2) ? 1 : (g == 5) ? 2 : -1;
}

// ---------------------------------------------------------------------------
// hs_type[t][c] = concat(Ws[t],Wt[t]) @ hs_W + hs_b   (6 x 128)
// hsW1[gi][t][c] = hs_type[t] @ mlp_w1[gi][0:128]     (3 x 6 x 128)
// ---------------------------------------------------------------------------
__global__ void precompute_kernel(const float* __restrict__ Ws,
                                  const float* __restrict__ Wt,
                                  const float* __restrict__ hs_W,
                                  const float* __restrict__ hs_b,
                                  const float* __restrict__ w1,
                                  float* __restrict__ hs_type,
                                  float* __restrict__ hsW1) {
    __shared__ float lht[6 * HD];
    for (int idx = threadIdx.x; idx < 6 * HD; idx += 256) {
        int t = idx >> 7, c = idx & 127;
        float acc = hs_b[c];
        for (int k = 0; k < HD; k++) acc = fmaf(Ws[t * HD + k], hs_W[k * HD + c], acc);
        for (int k = 0; k < HD; k++) acc = fmaf(Wt[t * HD + k], hs_W[(HD + k) * HD + c], acc);
        lht[idx] = acc;
        hs_type[idx] = acc;
    }
    __syncthreads();
    for (int idx = threadIdx.x; idx < 3 * 6 * HD; idx += 256) {
        int gi = idx / (6 * HD);
        int t = (idx >> 7) % 6;
        int c = idx & 127;
        const float* w = w1 + gi * (2 * HD * HD);  // top half rows 0..127
        float acc = 0.f;
        for (int k = 0; k < HD; k++) acc = fmaf(lht[t * HD + k], w[k * HD + c], acc);
        hsW1[idx] = acc;
    }
}

// wihT[gi][k][j] = gru_wih[gi][j][k]   (3 x 128 x 384)
__global__ void transpose_wih(const float* __restrict__ wih, float* __restrict__ wihT) {
    int idx = blockIdx.x * 256 + threadIdx.x;
    if (idx >= 3 * 384 * HD) return;
    int gi = idx / (384 * HD);
    int r = idx % (384 * HD);
    int j = r / HD;
    int k = r % HD;
    wihT[gi * (384 * HD) + k * 384 + j] = wih[idx];
}

// hs out + hf zero-init
__global__ void scatter_hs(const int* __restrict__ gate,
                           const float* __restrict__ hs_type,
                           float* __restrict__ out) {
    int idx = blockIdx.x * 256 + threadIdx.x;  // NN*32 threads
    if (idx >= NN * 32) return;
    int i = idx >> 5, q = idx & 31;
    const float4* ht4 = (const float4*)hs_type;
    float4 v = ht4[gate[i] * 32 + q];
    float4* o4 = (float4*)out;
    o4[idx] = v;
    o4[(size_t)NN * 32 + idx] = make_float4(0.f, 0.f, 0.f, 0.f);
}

__global__ void group_nodes(const int* __restrict__ gate, const int* __restrict__ lvl,
                            int* __restrict__ ncnt, int* __restrict__ nlist,
                            int* __restrict__ nslot) {
    int i = blockIdx.x * 256 + threadIdx.x;
    if (i >= NN) return;
    int gi = gi_of(gate[i]);
    int l = lvl[i];
    if (gi >= 0 && l >= 1) {
        int glob = (l - 1) * 3 + gi;
        int slot = atomicAdd(&ncnt[glob], 1);
        if (slot < CAPN) {
            nlist[glob * CAPN + slot] = i;
            nslot[i] = slot;
        }
    }
}

__global__ void group_edges(const int* __restrict__ gate, const int* __restrict__ lvl,
                            const int* __restrict__ ei, const int* __restrict__ nslot,
                            int* __restrict__ ecnt, int* __restrict__ esrc,
                            int* __restrict__ edsl) {
    int e = blockIdx.x * 256 + threadIdx.x;
    if (e >= NE) return;
    int d = ei[NE + e];
    int gi = gi_of(gate[d]);
    int l = lvl[d];
    if (gi >= 0 && l >= 1) {
        int glob = (l - 1) * 3 + gi;
        int slot = atomicAdd(&ecnt[glob], 1);
        if (slot < CAPE) {
            esrc[glob * CAPE + slot] = ei[e];
            edsl[glob * CAPE + slot] = nslot[d];
        }
    }
}

// ---------------------------------------------------------------------------
// Per-level fused 3-layer edge MLP + scatter-add into msg.
// grid = 3 groups x 171 tiles of 48 edges; block = 256.
// ---------------------------------------------------------------------------
__global__ __launch_bounds__(256) void msg_kernel(
    int level, const int* __restrict__ gate, const float* __restrict__ hf,
    const float* __restrict__ w1, const float* __restrict__ b1,
    const float* __restrict__ w2, const float* __restrict__ b2,
    const float* __restrict__ w3, const float* __restrict__ b3,
    const float* __restrict__ hsW1, const int* __restrict__ ecnt,
    const int* __restrict__ esrc, const int* __restrict__ edsl,
    float* __restrict__ msg) {
    int gi = blockIdx.x / 171;
    int tile = (blockIdx.x % 171) * ETILE;
    int glob = (level - 1) * 3 + gi;
    int cnt = ecnt[glob];
    if (cnt > CAPE) cnt = CAPE;
    if (tile >= cnt) return;
    int nv = min(ETILE, cnt - tile);

    __shared__ float A[ETILE][EPAD];
    __shared__ float B[ETILE][EPAD];
    __shared__ int sgt[ETILE];
    __shared__ int sdsl[ETILE];

    const int* es = esrc + glob * CAPE + tile;
    const int* ed = edsl + glob * CAPE + tile;
    int tid = threadIdx.x;
    int c4 = tid & 31;
    int r8 = tid >> 5;

    // stage hf[src] tile (rows >= nv zeroed)
    for (int rr = 0; rr < 6; rr++) {
        int row = rr * 8 + r8;
        float4 v = make_float4(0.f, 0.f, 0.f, 0.f);
        if (row < nv) {
            int s = es[row];
            v = *((const float4*)(hf + (size_t)s * HD + c4 * 4));
        }
        *((float4*)&A[row][c4 * 4]) = v;
    }
    if (tid < ETILE) {
        if (tid < nv) { sgt[tid] = gate[es[tid]]; sdsl[tid] = ed[tid]; }
        else          { sgt[tid] = 0;             sdsl[tid] = 0; }
    }
    __syncthreads();

    int r0 = r8 * 6;
    int c0 = c4 * 4;
    float4 acc[6];

    // layer 1: relu(hsW1[gi][gate_src] + hf @ W1_bot + b1) -> B
    {
#pragma unroll
        for (int i = 0; i < 6; i++) acc[i] = make_float4(0.f, 0.f, 0.f, 0.f);
        const float* W = w1 + gi * (2 * HD * HD) + HD * HD;  // bottom half
#pragma unroll 4
        for (int k = 0; k < HD; k++) {
            float4 w = *((const float4*)(W + k * HD + c0));
#pragma unroll
            for (int i = 0; i < 6; i++) {
                float a = A[r0 + i][k];
                acc[i].x = fmaf(a, w.x, acc[i].x);
                acc[i].y = fmaf(a, w.y, acc[i].y);
                acc[i].z = fmaf(a, w.z, acc[i].z);
                acc[i].w = fmaf(a, w.w, acc[i].w);
            }
        }
        float4 bb = *((const float4*)(b1 + gi * HD + c0));
#pragma unroll
        for (int i = 0; i < 6; i++) {
            float4 hw = *((const float4*)(hsW1 + ((size_t)(gi * 6 + sgt[r0 + i])) * HD + c0));
            float4 o;
            o.x = fmaxf(acc[i].x + hw.x + bb.x, 0.f);
            o.y = fmaxf(acc[i].y + hw.y + bb.y, 0.f);
            o.z = fmaxf(acc[i].z + hw.z + bb.z, 0.f);
            o.w = fmaxf(acc[i].w + hw.w + bb.w, 0.f);
            *((float4*)&B[r0 + i][c0]) = o;
        }
    }
    __syncthreads();

    // layer 2: relu(B @ W2 + b2) -> A
    {
#pragma unroll
        for (int i = 0; i < 6; i++) acc[i] = make_float4(0.f, 0.f, 0.f, 0.f);
        const float* W = w2 + gi * (HD * HD);
#pragma unroll 4
        for (int k = 0; k < HD; k++) {
            float4 w = *((const float4*)(W + k * HD + c0));
#pragma unroll
            for (int i = 0; i < 6; i++) {
                float a = B[r0 + i][k];
                acc[i].x = fmaf(a, w.x, acc[i].x);
                acc[i].y = fmaf(a, w.y, acc[i].y);
                acc[i].z = fmaf(a, w.z, acc[i].z);
                acc[i].w = fmaf(a, w.w, acc[i].w);
            }
        }
        float4 bb = *((const float4*)(b2 + gi * HD + c0));
#pragma unroll
        for (int i = 0; i < 6; i++) {
            float4 o;
            o.x = fmaxf(acc[i].x + bb.x, 0.f);
            o.y = fmaxf(acc[i].y + bb.y, 0.f);
            o.z = fmaxf(acc[i].z + bb.z, 0.f);
            o.w = fmaxf(acc[i].w + bb.w, 0.f);
            *((float4*)&A[r0 + i][c0]) = o;
        }
    }
    __syncthreads();

    // layer 3: A @ W3 + b3, atomic scatter-add into msg[gi][dslot]
    {
#pragma unroll
        for (int i = 0; i < 6; i++) acc[i] = make_float4(0.f, 0.f, 0.f, 0.f);
        const float* W = w3 + gi * (HD * HD);
#pragma unroll 4
        for (int k = 0; k < HD; k++) {
            float4 w = *((const float4*)(W + k * HD + c0));
#pragma unroll
            for (int i = 0; i < 6; i++) {
                float a = A[r0 + i][k];
                acc[i].x = fmaf(a, w.x, acc[i].x);
                acc[i].y = fmaf(a, w.y, acc[i].y);
                acc[i].z = fmaf(a, w.z, acc[i].z);
                acc[i].w = fmaf(a, w.w, acc[i].w);
            }
        }
        float4 bb = *((const float4*)(b3 + gi * HD + c0));
#pragma unroll
        for (int i = 0; i < 6; i++) {
            if (r0 + i < nv) {
                float* mrow = msg + ((size_t)(gi * CAPN + sdsl[r0 + i])) * HD + c0;
                atomicAdd(mrow + 0, acc[i].x + bb.x);
                atomicAdd(mrow + 1, acc[i].y + bb.y);
                atomicAdd(mrow + 2, acc[i].z + bb.z);
                atomicAdd(mrow + 3, acc[i].w + bb.w);
            }
        }
    }
}

// ---------------------------------------------------------------------------
// Per-level GRU: gin = msg @ wih.T + bih ; gh = bhh (h_old == 0)
// hf = (1-z)*tanh(i_n + r*h_n).  Re-zeroes consumed msg rows.
// grid = 3 groups x 256 tiles of 16 nodes; block = 256.
// ---------------------------------------------------------------------------
__global__ __launch_bounds__(256) void gru_kernel(
    int level, const int* __restrict__ ncnt, const int* __restrict__ nlist,
    const float* __restrict__ wihT, const float* __restrict__ bih,
    const float* __restrict__ bhh, float* __restrict__ msg,
    float* __restrict__ out) {
    int gi = blockIdx.x >> 8;
    int tile = (blockIdx.x & 255) << 4;
    int glob = (level - 1) * 3 + gi;
    int cnt = ncnt[glob];
    if (cnt > CAPN) cnt = CAPN;
    if (tile >= cnt) return;
    int nv = min(16, cnt - tile);

    __shared__ float M[16][EPAD];
    __shared__ int snode[16];
    int tid = threadIdx.x;
    {
        int c4 = tid & 31;
        int r8 = tid >> 5;
        float4* msg4 = (float4*)msg;
        for (int it = 0; it < 2; it++) {
            int row = it * 8 + r8;
            size_t off = ((size_t)(gi * CAPN + tile + row)) * 32 + c4;
            float4 v = msg4[off];
            *((float4*)&M[row][c4 * 4]) = v;
            msg4[off] = make_float4(0.f, 0.f, 0.f, 0.f);  // restore zero invariant
        }
        if (tid < 16) snode[tid] = (tid < nv) ? nlist[glob * CAPN + tile + tid] : -1;
    }
    __syncthreads();

    int r = tid >> 4;        // node row 0..15
    int c0 = (tid & 15) * 8; // 8 columns per thread
    float accr[8], accz[8], accn[8];
#pragma unroll
    for (int j = 0; j < 8; j++) { accr[j] = 0.f; accz[j] = 0.f; accn[j] = 0.f; }

    const float* wT = wihT + gi * (HD * 384);
#pragma unroll 2
    for (int k = 0; k < HD; k++) {
        float m = M[r][k];
        const float* wrow = wT + k * 384;
        float4 a0 = *((const float4*)(wrow + c0));
        float4 a1 = *((const float4*)(wrow + c0 + 4));
        float4 z0 = *((const float4*)(wrow + 128 + c0));
        float4 z1 = *((const float4*)(wrow + 128 + c0 + 4));
        float4 n0 = *((const float4*)(wrow + 256 + c0));
        float4 n1 = *((const float4*)(wrow + 256 + c0 + 4));
        accr[0] = fmaf(m, a0.x, accr[0]); accr[1] = fmaf(m, a0.y, accr[1]);
        accr[2] = fmaf(m, a0.z, accr[2]); accr[3] = fmaf(m, a0.w, accr[3]);
        accr[4] = fmaf(m, a1.x, accr[4]); accr[5] = fmaf(m, a1.y, accr[5]);
        accr[6] = fmaf(m, a1.z, accr[6]); accr[7] = fmaf(m, a1.w, accr[7]);
        accz[0] = fmaf(m, z0.x, accz[0]); accz[1] = fmaf(m, z0.y, accz[1]);
        accz[2] = fmaf(m, z0.z, accz[2]); accz[3] = fmaf(m, z0.w, accz[3]);
        accz[4] = fmaf(m, z1.x, accz[4]); accz[5] = fmaf(m, z1.y, accz[5]);
        accz[6] = fmaf(m, z1.z, accz[6]); accz[7] = fmaf(m, z1.w, accz[7]);
        accn[0] = fmaf(m, n0.x, accn[0]); accn[1] = fmaf(m, n0.y, accn[1]);
        accn[2] = fmaf(m, n0.z, accn[2]); accn[3] = fmaf(m, n0.w, accn[3]);
        accn[4] = fmaf(m, n1.x, accn[4]); accn[5] = fmaf(m, n1.y, accn[5]);
        accn[6] = fmaf(m, n1.z, accn[6]); accn[7] = fmaf(m, n1.w, accn[7]);
    }

    int n = snode[r];
    if (n >= 0) {
        const float* bi = bih + gi * 384;
        const float* bh = bhh + gi * 384;
        float outv[8];
#pragma unroll
        for (int j = 0; j < 8; j++) {
            int c = c0 + j;
            float ir = accr[j] + bi[c] + bh[c];
            float iz = accz[j] + bi[128 + c] + bh[128 + c];
            float inn = accn[j] + bi[256 + c];
            float hn = bh[256 + c];
            float rg = 1.f / (1.f + expf(-ir));
            float zg = 1.f / (1.f + expf(-iz));
            float nst = tanhf(inn + rg * hn);
            outv[j] = (1.f - zg) * nst;
        }
        float* orow = out + (size_t)NN * HD + (size_t)n * HD + c0;
        *((float4*)&orow[0]) = make_float4(outv[0], outv[1], outv[2], outv[3]);
        *((float4*)&orow[4]) = make_float4(outv[4], outv[5], outv[6], outv[7]);
    }
}

extern "C" void kernel_launch(void* const* d_in, const int* in_sizes, int n_in,
                              void* d_out, int out_size, void* d_ws, size_t ws_size,
                              hipStream_t stream) {
    const int* gate = (const int*)d_in[0];
    const int* lvl  = (const int*)d_in[1];
    const int* ei   = (const int*)d_in[2];
    const float* Ws   = (const float*)d_in[3];
    const float* Wt   = (const float*)d_in[4];
    const float* hs_W = (const float*)d_in[5];
    const float* hs_b = (const float*)d_in[6];
    const float* w1 = (const float*)d_in[7];
    const float* b1 = (const float*)d_in[8];
    const float* w2 = (const float*)d_in[9];
    const float* b2 = (const float*)d_in[10];
    const float* w3 = (const float*)d_in[11];
    const float* b3 = (const float*)d_in[12];
    const float* wih = (const float*)d_in[13];
    // d_in[14] = gru_whh: unused (h_old is provably zero for every updated node)
    const float* bih = (const float*)d_in[15];
    const float* bhh = (const float*)d_in[16];
    float* out = (float*)d_out;
    char* ws = (char*)d_ws;

    int*   ncnt    = (int*)(ws + OFF_NCNT);
    int*   ecnt    = (int*)(ws + OFF_ECNT);
    float* hs_type = (float*)(ws + OFF_HSTYPE);
    float* hsW1    = (float*)(ws + OFF_HSW1);
    float* wihT    = (float*)(ws + OFF_WIHT);
    int*   nlist   = (int*)(ws + OFF_NLIST);
    int*   nslot   = (int*)(ws + OFF_NSLOT);
    int*   esrc    = (int*)(ws + OFF_ESRC);
    int*   edsl    = (int*)(ws + OFF_EDSL);
    float* msg     = (float*)(ws + OFF_MSG);

    hipMemsetAsync(d_ws, 0, WS_USED, stream);

    precompute_kernel<<<1, 256, 0, stream>>>(Ws, Wt, hs_W, hs_b, w1, hs_type, hsW1);
    transpose_wih<<<(3 * 384 * HD + 255) / 256, 256, 0, stream>>>(wih, wihT);
    scatter_hs<<<(NN * 32) / 256, 256, 0, stream>>>(gate, hs_type, out);
    group_nodes<<<(NN + 255) / 256, 256, 0, stream>>>(gate, lvl, ncnt, nlist, nslot);
    group_edges<<<(NE + 255) / 256, 256, 0, stream>>>(gate, lvl, ei, nslot, ecnt, esrc, edsl);

    const float* hf = out + (size_t)NN * HD;
    for (int l = 1; l < 8; l++) {
        msg_kernel<<<3 * 171, 256, 0, stream>>>(l, gate, hf, w1, b1, w2, b2, w3, b3,
                                                hsW1, ecnt, esrc, edsl, msg);
        gru_kernel<<<3 * 256, 256, 0, stream>>>(l, ncnt, nlist, wihT, bih, bhh, msg, out);
    }
}

// Round 2
// 1193.518 us; speedup vs baseline: 1.2490x; 1.2490x over previous
//
#include <hip/hip_runtime.h>
#include <math.h>

#define NN 100000
#define NE 200000
#define HD 128
#define CAPN 4096
#define CAPE 8192
#define ETILE 48
#define EPAD 132
#define NGROUP 21
#define GBS 512

// workspace byte offsets (all 128B aligned)
#define OFF_NCNT   0          // 21 ints
#define OFF_ECNT   256        // 21 ints
#define OFF_HSTYPE 512        // 6*128 f32
#define OFF_HSW1   3584       // 3*6*128 f32
#define OFF_WIHT   12800      // 3*128*384 f32
#define OFF_NLIST  602624     // 21*4096 ints
#define OFF_NSLOT  946688     // NN ints
#define OFF_ESRC   1346688    // 21*8192 ints
#define OFF_EDSL   2034816    // 21*8192 ints
#define OFF_MSG    2722944    // 3*4096*128 f32
#define WS_USED    9014400

__device__ __forceinline__ int gi_of(int g) {
    // GATE_CODES = (3,2,5) -> gi 0,1,2
    return (g == 3) ? 0 : (g == 2) ? 1 : (g == 5) ? 2 : -1;
}

// ---------------------------------------------------------------------------
// hs_type[t][c] = concat(Ws[t],Wt[t]) @ hs_W + hs_b   (6 x 128)
// hsW1[gi][t][c] = hs_type[t] @ mlp_w1[gi][0:128]     (3 x 6 x 128)
// ---------------------------------------------------------------------------
__global__ void precompute_kernel(const float* __restrict__ Ws,
                                  const float* __restrict__ Wt,
                                  const float* __restrict__ hs_W,
                                  const float* __restrict__ hs_b,
                                  const float* __restrict__ w1,
                                  float* __restrict__ hs_type,
                                  float* __restrict__ hsW1) {
    __shared__ float lht[6 * HD];
    for (int idx = threadIdx.x; idx < 6 * HD; idx += 256) {
        int t = idx >> 7, c = idx & 127;
        float acc = hs_b[c];
        for (int k = 0; k < HD; k++) acc = fmaf(Ws[t * HD + k], hs_W[k * HD + c], acc);
        for (int k = 0; k < HD; k++) acc = fmaf(Wt[t * HD + k], hs_W[(HD + k) * HD + c], acc);
        lht[idx] = acc;
        hs_type[idx] = acc;
    }
    __syncthreads();
    for (int idx = threadIdx.x; idx < 3 * 6 * HD; idx += 256) {
        int gi = idx / (6 * HD);
        int t = (idx >> 7) % 6;
        int c = idx & 127;
        const float* w = w1 + gi * (2 * HD * HD);  // top half rows 0..127
        float acc = 0.f;
        for (int k = 0; k < HD; k++) acc = fmaf(lht[t * HD + k], w[k * HD + c], acc);
        hsW1[idx] = acc;
    }
}

// wihT[gi][k][j] = gru_wih[gi][j][k]   (3 x 128 x 384)
__global__ void transpose_wih(const float* __restrict__ wih, float* __restrict__ wihT) {
    int idx = blockIdx.x * 256 + threadIdx.x;
    if (idx >= 3 * 384 * HD) return;
    int gi = idx / (384 * HD);
    int r = idx % (384 * HD);
    int j = r / HD;
    int k = r % HD;
    wihT[gi * (384 * HD) + k * 384 + j] = wih[idx];
}

// hs out + hf zero-init
__global__ void scatter_hs(const int* __restrict__ gate,
                           const float* __restrict__ hs_type,
                           float* __restrict__ out) {
    int idx = blockIdx.x * 256 + threadIdx.x;  // NN*32 threads
    if (idx >= NN * 32) return;
    int i = idx >> 5, q = idx & 31;
    const float4* ht4 = (const float4*)hs_type;
    float4 v = ht4[gate[i] * 32 + q];
    float4* o4 = (float4*)out;
    o4[idx] = v;
    o4[(size_t)NN * 32 + idx] = make_float4(0.f, 0.f, 0.f, 0.f);
}

// ---------------------------------------------------------------------------
// LDS-aggregated grouping: per-block local counts -> one global atomic per
// (block, group) to reserve a contiguous range -> ordered writes.
// Cuts global atomics from 200K same-address ops to ~8K.
// ---------------------------------------------------------------------------
__global__ __launch_bounds__(GBS) void group_nodes(
    const int* __restrict__ gate, const int* __restrict__ lvl,
    int* __restrict__ ncnt, int* __restrict__ nlist, int* __restrict__ nslot) {
    __shared__ int lcnt[NGROUP];
    __shared__ int lbase[NGROUP];
    int tid = threadIdx.x;
    if (tid < NGROUP) lcnt[tid] = 0;
    __syncthreads();
    int i = blockIdx.x * GBS + tid;
    int glob = -1, local = 0;
    if (i < NN) {
        int gi = gi_of(gate[i]);
        int l = lvl[i];
        if (gi >= 0 && l >= 1) {
            glob = (l - 1) * 3 + gi;
            local = atomicAdd(&lcnt[glob], 1);
        }
    }
    __syncthreads();
    if (tid < NGROUP) {
        int c = lcnt[tid];
        lbase[tid] = c ? atomicAdd(&ncnt[tid], c) : 0;
    }
    __syncthreads();
    if (glob >= 0) {
        int slot = lbase[glob] + local;
        if (slot < CAPN) {
            nlist[glob * CAPN + slot] = i;
            nslot[i] = slot;
        }
    }
}

__global__ __launch_bounds__(GBS) void group_edges(
    const int* __restrict__ gate, const int* __restrict__ lvl,
    const int* __restrict__ ei, const int* __restrict__ nslot,
    int* __restrict__ ecnt, int* __restrict__ esrc, int* __restrict__ edsl) {
    __shared__ int lcnt[NGROUP];
    __shared__ int lbase[NGROUP];
    int tid = threadIdx.x;
    if (tid < NGROUP) lcnt[tid] = 0;
    __syncthreads();
    int e = blockIdx.x * GBS + tid;
    int glob = -1, local = 0, s = 0, dsl = 0;
    if (e < NE) {
        int d = ei[NE + e];
        int gi = gi_of(gate[d]);
        int l = lvl[d];
        if (gi >= 0 && l >= 1) {
            glob = (l - 1) * 3 + gi;
            local = atomicAdd(&lcnt[glob], 1);
            s = ei[e];
            dsl = nslot[d];
        }
    }
    __syncthreads();
    if (tid < NGROUP) {
        int c = lcnt[tid];
        lbase[tid] = c ? atomicAdd(&ecnt[tid], c) : 0;
    }
    __syncthreads();
    if (glob >= 0) {
        int slot = lbase[glob] + local;
        if (slot < CAPE) {
            esrc[glob * CAPE + slot] = s;
            edsl[glob * CAPE + slot] = dsl;
        }
    }
}

// ---------------------------------------------------------------------------
// Per-level fused 3-layer edge MLP + scatter-add into msg.
// grid = 3 groups x 171 tiles of 48 edges; block = 256.
// ---------------------------------------------------------------------------
__global__ __launch_bounds__(256) void msg_kernel(
    int level, const int* __restrict__ gate, const float* __restrict__ hf,
    const float* __restrict__ w1, const float* __restrict__ b1,
    const float* __restrict__ w2, const float* __restrict__ b2,
    const float* __restrict__ w3, const float* __restrict__ b3,
    const float* __restrict__ hsW1, const int* __restrict__ ecnt,
    const int* __restrict__ esrc, const int* __restrict__ edsl,
    float* __restrict__ msg) {
    int gi = blockIdx.x / 171;
    int tile = (blockIdx.x % 171) * ETILE;
    int glob = (level - 1) * 3 + gi;
    int cnt = ecnt[glob];
    if (cnt > CAPE) cnt = CAPE;
    if (tile >= cnt) return;
    int nv = min(ETILE, cnt - tile);

    __shared__ float A[ETILE][EPAD];
    __shared__ float B[ETILE][EPAD];
    __shared__ int sgt[ETILE];
    __shared__ int sdsl[ETILE];

    const int* es = esrc + glob * CAPE + tile;
    const int* ed = edsl + glob * CAPE + tile;
    int tid = threadIdx.x;
    int c4 = tid & 31;
    int r8 = tid >> 5;

    // stage hf[src] tile (rows >= nv zeroed)
    for (int rr = 0; rr < 6; rr++) {
        int row = rr * 8 + r8;
        float4 v = make_float4(0.f, 0.f, 0.f, 0.f);
        if (row < nv) {
            int s = es[row];
            v = *((const float4*)(hf + (size_t)s * HD + c4 * 4));
        }
        *((float4*)&A[row][c4 * 4]) = v;
    }
    if (tid < ETILE) {
        if (tid < nv) { sgt[tid] = gate[es[tid]]; sdsl[tid] = ed[tid]; }
        else          { sgt[tid] = 0;             sdsl[tid] = 0; }
    }
    __syncthreads();

    int r0 = r8 * 6;
    int c0 = c4 * 4;
    float4 acc[6];

    // layer 1: relu(hsW1[gi][gate_src] + hf @ W1_bot + b1) -> B
    {
#pragma unroll
        for (int i = 0; i < 6; i++) acc[i] = make_float4(0.f, 0.f, 0.f, 0.f);
        const float* W = w1 + gi * (2 * HD * HD) + HD * HD;  // bottom half
#pragma unroll 4
        for (int k = 0; k < HD; k++) {
            float4 w = *((const float4*)(W + k * HD + c0));
#pragma unroll
            for (int i = 0; i < 6; i++) {
                float a = A[r0 + i][k];
                acc[i].x = fmaf(a, w.x, acc[i].x);
                acc[i].y = fmaf(a, w.y, acc[i].y);
                acc[i].z = fmaf(a, w.z, acc[i].z);
                acc[i].w = fmaf(a, w.w, acc[i].w);
            }
        }
        float4 bb = *((const float4*)(b1 + gi * HD + c0));
#pragma unroll
        for (int i = 0; i < 6; i++) {
            float4 hw = *((const float4*)(hsW1 + ((size_t)(gi * 6 + sgt[r0 + i])) * HD + c0));
            float4 o;
            o.x = fmaxf(acc[i].x + hw.x + bb.x, 0.f);
            o.y = fmaxf(acc[i].y + hw.y + bb.y, 0.f);
            o.z = fmaxf(acc[i].z + hw.z + bb.z, 0.f);
            o.w = fmaxf(acc[i].w + hw.w + bb.w, 0.f);
            *((float4*)&B[r0 + i][c0]) = o;
        }
    }
    __syncthreads();

    // layer 2: relu(B @ W2 + b2) -> A
    {
#pragma unroll
        for (int i = 0; i < 6; i++) acc[i] = make_float4(0.f, 0.f, 0.f, 0.f);
        const float* W = w2 + gi * (HD * HD);
#pragma unroll 4
        for (int k = 0; k < HD; k++) {
            float4 w = *((const float4*)(W + k * HD + c0));
#pragma unroll
            for (int i = 0; i < 6; i++) {
                float a = B[r0 + i][k];
                acc[i].x = fmaf(a, w.x, acc[i].x);
                acc[i].y = fmaf(a, w.y, acc[i].y);
                acc[i].z = fmaf(a, w.z, acc[i].z);
                acc[i].w = fmaf(a, w.w, acc[i].w);
            }
        }
        float4 bb = *((const float4*)(b2 + gi * HD + c0));
#pragma unroll
        for (int i = 0; i < 6; i++) {
            float4 o;
            o.x = fmaxf(acc[i].x + bb.x, 0.f);
            o.y = fmaxf(acc[i].y + bb.y, 0.f);
            o.z = fmaxf(acc[i].z + bb.z, 0.f);
            o.w = fmaxf(acc[i].w + bb.w, 0.f);
            *((float4*)&A[r0 + i][c0]) = o;
        }
    }
    __syncthreads();

    // layer 3: A @ W3 + b3, atomic scatter-add into msg[gi][dslot]
    {
#pragma unroll
        for (int i = 0; i < 6; i++) acc[i] = make_float4(0.f, 0.f, 0.f, 0.f);
        const float* W = w3 + gi * (HD * HD);
#pragma unroll 4
        for (int k = 0; k < HD; k++) {
            float4 w = *((const float4*)(W + k * HD + c0));
#pragma unroll
            for (int i = 0; i < 6; i++) {
                float a = A[r0 + i][k];
                acc[i].x = fmaf(a, w.x, acc[i].x);
                acc[i].y = fmaf(a, w.y, acc[i].y);
                acc[i].z = fmaf(a, w.z, acc[i].z);
                acc[i].w = fmaf(a, w.w, acc[i].w);
            }
        }
        float4 bb = *((const float4*)(b3 + gi * HD + c0));
#pragma unroll
        for (int i = 0; i < 6; i++) {
            if (r0 + i < nv) {
                float* mrow = msg + ((size_t)(gi * CAPN + sdsl[r0 + i])) * HD + c0;
                atomicAdd(mrow + 0, acc[i].x + bb.x);
                atomicAdd(mrow + 1, acc[i].y + bb.y);
                atomicAdd(mrow + 2, acc[i].z + bb.z);
                atomicAdd(mrow + 3, acc[i].w + bb.w);
            }
        }
    }
}

// ---------------------------------------------------------------------------
// Per-level GRU: gin = msg @ wih.T + bih ; gh = bhh (h_old == 0)
// hf = (1-z)*tanh(i_n + r*h_n).  Re-zeroes consumed msg rows.
// grid = 3 groups x 256 tiles of 16 nodes; block = 256.
// ---------------------------------------------------------------------------
__global__ __launch_bounds__(256) void gru_kernel(
    int level, const int* __restrict__ ncnt, const int* __restrict__ nlist,
    const float* __restrict__ wihT, const float* __restrict__ bih,
    const float* __restrict__ bhh, float* __restrict__ msg,
    float* __restrict__ out) {
    int gi = blockIdx.x >> 8;
    int tile = (blockIdx.x & 255) << 4;
    int glob = (level - 1) * 3 + gi;
    int cnt = ncnt[glob];
    if (cnt > CAPN) cnt = CAPN;
    if (tile >= cnt) return;
    int nv = min(16, cnt - tile);

    __shared__ float M[16][EPAD];
    __shared__ int snode[16];
    int tid = threadIdx.x;
    {
        int c4 = tid & 31;
        int r8 = tid >> 5;
        float4* msg4 = (float4*)msg;
        for (int it = 0; it < 2; it++) {
            int row = it * 8 + r8;
            size_t off = ((size_t)(gi * CAPN + tile + row)) * 32 + c4;
            float4 v = msg4[off];
            *((float4*)&M[row][c4 * 4]) = v;
            msg4[off] = make_float4(0.f, 0.f, 0.f, 0.f);  // restore zero invariant
        }
        if (tid < 16) snode[tid] = (tid < nv) ? nlist[glob * CAPN + tile + tid] : -1;
    }
    __syncthreads();

    int r = tid >> 4;        // node row 0..15
    int c0 = (tid & 15) * 8; // 8 columns per thread
    float accr[8], accz[8], accn[8];
#pragma unroll
    for (int j = 0; j < 8; j++) { accr[j] = 0.f; accz[j] = 0.f; accn[j] = 0.f; }

    const float* wT = wihT + gi * (HD * 384);
#pragma unroll 2
    for (int k = 0; k < HD; k++) {
        float m = M[r][k];
        const float* wrow = wT + k * 384;
        float4 a0 = *((const float4*)(wrow + c0));
        float4 a1 = *((const float4*)(wrow + c0 + 4));
        float4 z0 = *((const float4*)(wrow + 128 + c0));
        float4 z1 = *((const float4*)(wrow + 128 + c0 + 4));
        float4 n0 = *((const float4*)(wrow + 256 + c0));
        float4 n1 = *((const float4*)(wrow + 256 + c0 + 4));
        accr[0] = fmaf(m, a0.x, accr[0]); accr[1] = fmaf(m, a0.y, accr[1]);
        accr[2] = fmaf(m, a0.z, accr[2]); accr[3] = fmaf(m, a0.w, accr[3]);
        accr[4] = fmaf(m, a1.x, accr[4]); accr[5] = fmaf(m, a1.y, accr[5]);
        accr[6] = fmaf(m, a1.z, accr[6]); accr[7] = fmaf(m, a1.w, accr[7]);
        accz[0] = fmaf(m, z0.x, accz[0]); accz[1] = fmaf(m, z0.y, accz[1]);
        accz[2] = fmaf(m, z0.z, accz[2]); accz[3] = fmaf(m, z0.w, accz[3]);
        accz[4] = fmaf(m, z1.x, accz[4]); accz[5] = fmaf(m, z1.y, accz[5]);
        accz[6] = fmaf(m, z1.z, accz[6]); accz[7] = fmaf(m, z1.w, accz[7]);
        accn[0] = fmaf(m, n0.x, accn[0]); accn[1] = fmaf(m, n0.y, accn[1]);
        accn[2] = fmaf(m, n0.z, accn[2]); accn[3] = fmaf(m, n0.w, accn[3]);
        accn[4] = fmaf(m, n1.x, accn[4]); accn[5] = fmaf(m, n1.y, accn[5]);
        accn[6] = fmaf(m, n1.z, accn[6]); accn[7] = fmaf(m, n1.w, accn[7]);
    }

    int n = snode[r];
    if (n >= 0) {
        const float* bi = bih + gi * 384;
        const float* bh = bhh + gi * 384;
        float outv[8];
#pragma unroll
        for (int j = 0; j < 8; j++) {
            int c = c0 + j;
            float ir = accr[j] + bi[c] + bh[c];
            float iz = accz[j] + bi[128 + c] + bh[128 + c];
            float inn = accn[j] + bi[256 + c];
            float hn = bh[256 + c];
            float rg = 1.f / (1.f + expf(-ir));
            float zg = 1.f / (1.f + expf(-iz));
            float nst = tanhf(inn + rg * hn);
            outv[j] = (1.f - zg) * nst;
        }
        float* orow = out + (size_t)NN * HD + (size_t)n * HD + c0;
        *((float4*)&orow[0]) = make_float4(outv[0], outv[1], outv[2], outv[3]);
        *((float4*)&orow[4]) = make_float4(outv[4], outv[5], outv[6], outv[7]);
    }
}

extern "C" void kernel_launch(void* const* d_in, const int* in_sizes, int n_in,
                              void* d_out, int out_size, void* d_ws, size_t ws_size,
                              hipStream_t stream) {
    const int* gate = (const int*)d_in[0];
    const int* lvl  = (const int*)d_in[1];
    const int* ei   = (const int*)d_in[2];
    const float* Ws   = (const float*)d_in[3];
    const float* Wt   = (const float*)d_in[4];
    const float* hs_W = (const float*)d_in[5];
    const float* hs_b = (const float*)d_in[6];
    const float* w1 = (const float*)d_in[7];
    const float* b1 = (const float*)d_in[8];
    const float* w2 = (const float*)d_in[9];
    const float* b2 = (const float*)d_in[10];
    const float* w3 = (const float*)d_in[11];
    const float* b3 = (const float*)d_in[12];
    const float* wih = (const float*)d_in[13];
    // d_in[14] = gru_whh: unused (h_old is provably zero for every updated node)
    const float* bih = (const float*)d_in[15];
    const float* bhh = (const float*)d_in[16];
    float* out = (float*)d_out;
    char* ws = (char*)d_ws;

    int*   ncnt    = (int*)(ws + OFF_NCNT);
    int*   ecnt    = (int*)(ws + OFF_ECNT);
    float* hs_type = (float*)(ws + OFF_HSTYPE);
    float* hsW1    = (float*)(ws + OFF_HSW1);
    float* wihT    = (float*)(ws + OFF_WIHT);
    int*   nlist   = (int*)(ws + OFF_NLIST);
    int*   nslot   = (int*)(ws + OFF_NSLOT);
    int*   esrc    = (int*)(ws + OFF_ESRC);
    int*   edsl    = (int*)(ws + OFF_EDSL);
    float* msg     = (float*)(ws + OFF_MSG);

    hipMemsetAsync(d_ws, 0, WS_USED, stream);

    precompute_kernel<<<1, 256, 0, stream>>>(Ws, Wt, hs_W, hs_b, w1, hs_type, hsW1);
    transpose_wih<<<(3 * 384 * HD + 255) / 256, 256, 0, stream>>>(wih, wihT);
    scatter_hs<<<(NN * 32) / 256, 256, 0, stream>>>(gate, hs_type, out);
    group_nodes<<<(NN + GBS - 1) / GBS, GBS, 0, stream>>>(gate, lvl, ncnt, nlist, nslot);
    group_edges<<<(NE + GBS - 1) / GBS, GBS, 0, stream>>>(gate, lvl, ei, nslot, ecnt, esrc, edsl);

    const float* hf = out + (size_t)NN * HD;
    for (int l = 1; l < 8; l++) {
        msg_kernel<<<3 * 171, 256, 0, stream>>>(l, gate, hf, w1, b1, w2, b2, w3, b3,
                                                hsW1, ecnt, esrc, edsl, msg);
        gru_kernel<<<3 * 256, 256, 0, stream>>>(l, ncnt, nlist, wihT, bih, bhh, msg, out);
    }
}

// Round 3
// 469.863 us; speedup vs baseline: 3.1726x; 2.5401x over previous
//
#include <hip/hip_runtime.h>
#include <math.h>

#define NN 100000
#define NE 200000
#define HD 128
#define CAPN 4096
#define CAPE 8192
#define NGROUP 21
#define GBS 512
#define AP 136   // bf16 LDS row pitch (128 + 8 pad -> breaks bank alignment)

typedef short bf16x8 __attribute__((ext_vector_type(8)));
typedef float f32x4 __attribute__((ext_vector_type(4)));

// workspace byte offsets (128B aligned)
#define OFF_NCNT   0          // 21 ints
#define OFF_ECNT   256        // 21 ints
#define OFF_HSTYPE 512        // 6*128 f32
#define OFF_HSW1   3584       // 3*6*128 f32 (fp32, kept full precision)
#define OFF_WBMLP  12800      // 3 gi x 3 layer x 16384 bf16 (swizzled B-frags)
#define OFF_WBIH   307712     // 3 gi x 49152 bf16 (wih^T swizzled B-frags)
#define OFF_NLIST  602624     // 21*4096 ints
#define OFF_NSLOT  946688     // NN ints
#define OFF_ESRC   1346688    // 21*8192 ints
#define OFF_EDSL   2034816    // 21*8192 ints
#define OFF_MSG    2722944    // 3*4096*128 f32
#define WS_USED    9014400

__device__ __forceinline__ int gi_of(int g) {
    return (g == 3) ? 0 : (g == 2) ? 1 : (g == 5) ? 2 : -1;
}

__device__ __forceinline__ unsigned short f2bf(float f) {
    unsigned int u = __float_as_uint(f);
    u += 0x7FFF + ((u >> 16) & 1);   // RNE
    return (unsigned short)(u >> 16);
}

// ---------------------------------------------------------------------------
// hs_type[t][c] = concat(Ws[t],Wt[t]) @ hs_W + hs_b   (6 x 128)   fp32
// hsW1[gi][t][c] = hs_type[t] @ mlp_w1[gi][0:128]     (3 x 6 x 128) fp32
// ---------------------------------------------------------------------------
__global__ void precompute_kernel(const float* __restrict__ Ws,
                                  const float* __restrict__ Wt,
                                  const float* __restrict__ hs_W,
                                  const float* __restrict__ hs_b,
                                  const float* __restrict__ w1,
                                  float* __restrict__ hs_type,
                                  float* __restrict__ hsW1) {
    __shared__ float lht[6 * HD];
    for (int idx = threadIdx.x; idx < 6 * HD; idx += 256) {
        int t = idx >> 7, c = idx & 127;
        float acc = hs_b[c];
        for (int k = 0; k < HD; k++) acc = fmaf(Ws[t * HD + k], hs_W[k * HD + c], acc);
        for (int k = 0; k < HD; k++) acc = fmaf(Wt[t * HD + k], hs_W[(HD + k) * HD + c], acc);
        lht[idx] = acc;
        hs_type[idx] = acc;
    }
    __syncthreads();
    for (int idx = threadIdx.x; idx < 3 * 6 * HD; idx += 256) {
        int gi = idx / (6 * HD);
        int t = (idx >> 7) % 6;
        int c = idx & 127;
        const float* w = w1 + gi * (2 * HD * HD);  // top half rows 0..127
        float acc = 0.f;
        for (int k = 0; k < HD; k++) acc = fmaf(lht[t * HD + k], w[k * HD + c], acc);
        hsW1[idx] = acc;
    }
}

// ---------------------------------------------------------------------------
// Swizzle all GEMM weights into bf16 MFMA B-fragment layout:
// for B[K][N]: dst[((nt*4+kc)*64 + L)*8 + j], L=(kq<<4)|(n&15), k=kc*32+kq*8+j
// One 16B load per lane per fragment at runtime.
// ---------------------------------------------------------------------------
__global__ void swizzle_weights(const float* __restrict__ w1,
                                const float* __restrict__ w2,
                                const float* __restrict__ w3,
                                const float* __restrict__ wih,
                                unsigned short* __restrict__ wbmlp,
                                unsigned short* __restrict__ wbih) {
    int id = blockIdx.x * 256 + threadIdx.x;
    if (id < 3 * 3 * 16384) {
        int gi = id / 49152;
        int rem = id % 49152;
        int layer = rem / 16384;
        int e = rem % 16384;
        int k = e >> 7, n = e & 127;
        float v;
        if (layer == 0)      v = w1[gi * (2 * HD * HD) + (HD + k) * HD + n];  // bottom half
        else if (layer == 1) v = w2[gi * (HD * HD) + k * HD + n];
        else                 v = w3[gi * (HD * HD) + k * HD + n];
        int nt = n >> 4, kc = k >> 5, kq = (k >> 3) & 3, j = k & 7;
        int L = (kq << 4) | (n & 15);
        wbmlp[(size_t)(gi * 3 + layer) * 16384 + ((nt * 4 + kc) * 64 + L) * 8 + j] = f2bf(v);
    } else {
        int id2 = id - 3 * 3 * 16384;
        if (id2 >= 3 * 49152) return;
        int gi = id2 / 49152;
        int e = id2 % 49152;
        int k = e / 384, n = e % 384;             // B[k][n] = wih[n][k]
        float v = wih[gi * (384 * HD) + n * HD + k];
        int nt = n >> 4, kc = k >> 5, kq = (k >> 3) & 3, j = k & 7;
        int L = (kq << 4) | (n & 15);
        wbih[(size_t)gi * 49152 + ((nt * 4 + kc) * 64 + L) * 8 + j] = f2bf(v);
    }
}

// hs out + hf zero-init
__global__ void scatter_hs(const int* __restrict__ gate,
                           const float* __restrict__ hs_type,
                           float* __restrict__ out) {
    int idx = blockIdx.x * 256 + threadIdx.x;  // NN*32 threads
    if (idx >= NN * 32) return;
    int i = idx >> 5, q = idx & 31;
    const float4* ht4 = (const float4*)hs_type;
    float4 v = ht4[gate[i] * 32 + q];
    float4* o4 = (float4*)out;
    o4[idx] = v;
    o4[(size_t)NN * 32 + idx] = make_float4(0.f, 0.f, 0.f, 0.f);
}

// ---------------------------------------------------------------------------
// LDS-aggregated grouping (one global atomic per block per non-empty group)
// ---------------------------------------------------------------------------
__global__ __launch_bounds__(GBS) void group_nodes(
    const int* __restrict__ gate, const int* __restrict__ lvl,
    int* __restrict__ ncnt, int* __restrict__ nlist, int* __restrict__ nslot) {
    __shared__ int lcnt[NGROUP];
    __shared__ int lbase[NGROUP];
    int tid = threadIdx.x;
    if (tid < NGROUP) lcnt[tid] = 0;
    __syncthreads();
    int i = blockIdx.x * GBS + tid;
    int glob = -1, local = 0;
    if (i < NN) {
        int gi = gi_of(gate[i]);
        int l = lvl[i];
        if (gi >= 0 && l >= 1) {
            glob = (l - 1) * 3 + gi;
            local = atomicAdd(&lcnt[glob], 1);
        }
    }
    __syncthreads();
    if (tid < NGROUP) {
        int c = lcnt[tid];
        lbase[tid] = c ? atomicAdd(&ncnt[tid], c) : 0;
    }
    __syncthreads();
    if (glob >= 0) {
        int slot = lbase[glob] + local;
        if (slot < CAPN) {
            nlist[glob * CAPN + slot] = i;
            nslot[i] = slot;
        }
    }
}

__global__ __launch_bounds__(GBS) void group_edges(
    const int* __restrict__ gate, const int* __restrict__ lvl,
    const int* __restrict__ ei, const int* __restrict__ nslot,
    int* __restrict__ ecnt, int* __restrict__ esrc, int* __restrict__ edsl) {
    __shared__ int lcnt[NGROUP];
    __shared__ int lbase[NGROUP];
    int tid = threadIdx.x;
    if (tid < NGROUP) lcnt[tid] = 0;
    __syncthreads();
    int e = blockIdx.x * GBS + tid;
    int glob = -1, local = 0, s = 0, dsl = 0;
    if (e < NE) {
        int d = ei[NE + e];
        int gi = gi_of(gate[d]);
        int l = lvl[d];
        if (gi >= 0 && l >= 1) {
            glob = (l - 1) * 3 + gi;
            local = atomicAdd(&lcnt[glob], 1);
            s = ei[e];
            dsl = nslot[d];
        }
    }
    __syncthreads();
    if (tid < NGROUP) {
        int c = lcnt[tid];
        lbase[tid] = c ? atomicAdd(&ecnt[tid], c) : 0;
    }
    __syncthreads();
    if (glob >= 0) {
        int slot = lbase[glob] + local;
        if (slot < CAPE) {
            esrc[glob * CAPE + slot] = s;
            edsl[glob * CAPE + slot] = dsl;
        }
    }
}

// ---------------------------------------------------------------------------
// MFMA 3-layer edge MLP + scatter-add. 64 edges/block, 4 waves x 16-row bands.
// Wave bands are self-contained: no inter-layer barriers; in-place LDS tile.
// grid = 3 groups x 128 tiles.
// ---------------------------------------------------------------------------
__global__ __launch_bounds__(256) void msg_kernel(
    int level, const int* __restrict__ gate, const float* __restrict__ hf,
    const unsigned short* __restrict__ wbmlp,
    const float* __restrict__ b1, const float* __restrict__ b2,
    const float* __restrict__ b3, const float* __restrict__ hsW1,
    const int* __restrict__ ecnt, const int* __restrict__ esrc,
    const int* __restrict__ edsl, float* __restrict__ msg) {
    int gi = blockIdx.x >> 7;
    int tile = (blockIdx.x & 127) * 64;
    int glob = (level - 1) * 3 + gi;
    int cnt = ecnt[glob]; if (cnt > CAPE) cnt = CAPE;
    if (tile >= cnt) return;
    int nv = min(64, cnt - tile);

    __shared__ unsigned short A[64 * AP];
    __shared__ float hsw[6 * 132];
    __shared__ int sgt[64];
    __shared__ int sdsl[64];

    int tid = threadIdx.x;
    const int* es = esrc + glob * CAPE + tile;
    const int* ed = edsl + glob * CAPE + tile;

    for (int i = tid; i < 6 * 132; i += 256) {
        int t = i / 132, c = i % 132;
        hsw[i] = (c < HD) ? hsW1[(gi * 6 + t) * HD + c] : 0.f;
    }
    {
        int row = tid >> 2, q = tid & 3;
        unsigned int* Au = (unsigned int*)A;
        int base = (row * AP + q * 32) >> 1;
        if (row < nv) {
            int s = es[row];
            const float4* src4 = (const float4*)(hf + (size_t)s * HD + q * 32);
#pragma unroll
            for (int i = 0; i < 8; i++) {
                float4 v = src4[i];
                Au[base + i * 2]     = f2bf(v.x) | ((unsigned int)f2bf(v.y) << 16);
                Au[base + i * 2 + 1] = f2bf(v.z) | ((unsigned int)f2bf(v.w) << 16);
            }
        } else {
#pragma unroll
            for (int i = 0; i < 16; i++) Au[base + i] = 0u;
        }
    }
    if (tid < 64) {
        sgt[tid]  = (tid < nv) ? gate[es[tid]] : 0;
        sdsl[tid] = (tid < nv) ? ed[tid] : 0;
    }
    __syncthreads();

    int ln = tid & 63, wv = tid >> 6;
    int lc = ln & 15, quad = ln >> 4;
    int rbase = wv * 16;
    const unsigned short* WB = wbmlp + (size_t)gi * 3 * 16384;

    float b1v[8], b2v[8], b3v[8];
#pragma unroll
    for (int nt = 0; nt < 8; nt++) {
        b1v[nt] = b1[gi * HD + nt * 16 + lc];
        b2v[nt] = b2[gi * HD + nt * 16 + lc];
        b3v[nt] = b3[gi * HD + nt * 16 + lc];
    }

    // ---- layer 1: relu(hsW1[gate_src] + hf@W1bot + b1), in-place ----
    {
        bf16x8 af[4];
#pragma unroll
        for (int kc = 0; kc < 4; kc++)
            af[kc] = *(bf16x8*)&A[(rbase + lc) * AP + kc * 32 + quad * 8];
        for (int nt = 0; nt < 8; nt++) {
            f32x4 acc = {0.f, 0.f, 0.f, 0.f};
#pragma unroll
            for (int kc = 0; kc < 4; kc++) {
                bf16x8 bf = *(const bf16x8*)&WB[((nt * 4 + kc) * 64 + ln) * 8];
                acc = __builtin_amdgcn_mfma_f32_16x16x32_bf16(af[kc], bf, acc, 0, 0, 0);
            }
#pragma unroll
            for (int r = 0; r < 4; r++) {
                int row = rbase + quad * 4 + r;
                float v = acc[r] + hsw[sgt[row] * 132 + nt * 16 + lc] + b1v[nt];
                A[row * AP + nt * 16 + lc] = f2bf(fmaxf(v, 0.f));
            }
        }
    }
    // ---- layer 2 ----
    {
        bf16x8 af[4];
#pragma unroll
        for (int kc = 0; kc < 4; kc++)
            af[kc] = *(bf16x8*)&A[(rbase + lc) * AP + kc * 32 + quad * 8];
        for (int nt = 0; nt < 8; nt++) {
            f32x4 acc = {0.f, 0.f, 0.f, 0.f};
#pragma unroll
            for (int kc = 0; kc < 4; kc++) {
                bf16x8 bf = *(const bf16x8*)&WB[16384 + ((nt * 4 + kc) * 64 + ln) * 8];
                acc = __builtin_amdgcn_mfma_f32_16x16x32_bf16(af[kc], bf, acc, 0, 0, 0);
            }
#pragma unroll
            for (int r = 0; r < 4; r++) {
                int row = rbase + quad * 4 + r;
                A[row * AP + nt * 16 + lc] = f2bf(fmaxf(acc[r] + b2v[nt], 0.f));
            }
        }
    }
    // ---- layer 3 + scatter-add ----
    {
        bf16x8 af[4];
#pragma unroll
        for (int kc = 0; kc < 4; kc++)
            af[kc] = *(bf16x8*)&A[(rbase + lc) * AP + kc * 32 + quad * 8];
        for (int nt = 0; nt < 8; nt++) {
            f32x4 acc = {0.f, 0.f, 0.f, 0.f};
#pragma unroll
            for (int kc = 0; kc < 4; kc++) {
                bf16x8 bf = *(const bf16x8*)&WB[2 * 16384 + ((nt * 4 + kc) * 64 + ln) * 8];
                acc = __builtin_amdgcn_mfma_f32_16x16x32_bf16(af[kc], bf, acc, 0, 0, 0);
            }
#pragma unroll
            for (int r = 0; r < 4; r++) {
                int row = rbase + quad * 4 + r;
                if (row < nv)
                    atomicAdd(&msg[((size_t)(gi * CAPN) + sdsl[row]) * HD + nt * 16 + lc],
                              acc[r] + b3v[nt]);
            }
        }
    }
}

// ---------------------------------------------------------------------------
// MFMA GRU: gin = msg @ wih.T + bih ; gh = bhh (h_old == 0).
// 64 nodes/block; r/z/n column-tiles share a lane -> all-register epilogue.
// Re-zeroes consumed msg rows. grid = 3 groups x 64 tiles.
// ---------------------------------------------------------------------------
__global__ __launch_bounds__(256) void gru_kernel(
    int level, const int* __restrict__ ncnt, const int* __restrict__ nlist,
    const unsigned short* __restrict__ wbih, const float* __restrict__ bih,
    const float* __restrict__ bhh, float* __restrict__ msg,
    float* __restrict__ out) {
    int gi = blockIdx.x >> 6;
    int tile = (blockIdx.x & 63) * 64;
    int glob = (level - 1) * 3 + gi;
    int cnt = ncnt[glob]; if (cnt > CAPN) cnt = CAPN;
    if (tile >= cnt) return;
    int nv = min(64, cnt - tile);

    __shared__ unsigned short M[64 * AP];
    __shared__ int snode[64];
    int tid = threadIdx.x;
    {
        int row = tid >> 2, q = tid & 3;
        float4* msg4 = (float4*)(msg + ((size_t)(gi * CAPN + tile + row)) * HD + q * 32);
        unsigned int* Mu = (unsigned int*)M;
        int base = (row * AP + q * 32) >> 1;
#pragma unroll
        for (int i = 0; i < 8; i++) {
            float4 v = msg4[i];
            Mu[base + i * 2]     = f2bf(v.x) | ((unsigned int)f2bf(v.y) << 16);
            Mu[base + i * 2 + 1] = f2bf(v.z) | ((unsigned int)f2bf(v.w) << 16);
            msg4[i] = make_float4(0.f, 0.f, 0.f, 0.f);  // restore zero invariant
        }
    }
    if (tid < 64) snode[tid] = (tid < nv) ? nlist[glob * CAPN + tile + tid] : -1;
    __syncthreads();

    int ln = tid & 63, wv = tid >> 6;
    int lc = ln & 15, quad = ln >> 4;
    int rbase = wv * 16;
    const unsigned short* WB = wbih + (size_t)gi * 49152;

    bf16x8 af[4];
#pragma unroll
    for (int kc = 0; kc < 4; kc++)
        af[kc] = *(bf16x8*)&M[(rbase + lc) * AP + kc * 32 + quad * 8];

    float* hfout = out + (size_t)NN * HD;
    for (int nt = 0; nt < 8; nt++) {
        f32x4 aR = {0.f, 0.f, 0.f, 0.f};
        f32x4 aZ = {0.f, 0.f, 0.f, 0.f};
        f32x4 aN = {0.f, 0.f, 0.f, 0.f};
#pragma unroll
        for (int kc = 0; kc < 4; kc++) {
            bf16x8 bR = *(const bf16x8*)&WB[(((nt)      * 4 + kc) * 64 + ln) * 8];
            bf16x8 bZ = *(const bf16x8*)&WB[(((nt + 8)  * 4 + kc) * 64 + ln) * 8];
            bf16x8 bN = *(const bf16x8*)&WB[(((nt + 16) * 4 + kc) * 64 + ln) * 8];
            aR = __builtin_amdgcn_mfma_f32_16x16x32_bf16(af[kc], bR, aR, 0, 0, 0);
            aZ = __builtin_amdgcn_mfma_f32_16x16x32_bf16(af[kc], bZ, aZ, 0, 0, 0);
            aN = __builtin_amdgcn_mfma_f32_16x16x32_bf16(af[kc], bN, aN, 0, 0, 0);
        }
        int c = nt * 16 + lc;
        float biR = bih[gi * 384 + c],       bhR = bhh[gi * 384 + c];
        float biZ = bih[gi * 384 + 128 + c], bhZ = bhh[gi * 384 + 128 + c];
        float biN = bih[gi * 384 + 256 + c], bhN = bhh[gi * 384 + 256 + c];
#pragma unroll
        for (int r = 0; r < 4; r++) {
            int row = rbase + quad * 4 + r;
            int n = snode[row];
            if (n >= 0) {
                float ir = aR[r] + biR + bhR;
                float iz = aZ[r] + biZ + bhZ;
                float inn = aN[r] + biN;
                float rg = 1.f / (1.f + expf(-ir));
                float zg = 1.f / (1.f + expf(-iz));
                float nst = tanhf(inn + rg * bhN);
                hfout[(size_t)n * HD + c] = (1.f - zg) * nst;
            }
        }
    }
}

extern "C" void kernel_launch(void* const* d_in, const int* in_sizes, int n_in,
                              void* d_out, int out_size, void* d_ws, size_t ws_size,
                              hipStream_t stream) {
    const int* gate = (const int*)d_in[0];
    const int* lvl  = (const int*)d_in[1];
    const int* ei   = (const int*)d_in[2];
    const float* Ws   = (const float*)d_in[3];
    const float* Wt   = (const float*)d_in[4];
    const float* hs_W = (const float*)d_in[5];
    const float* hs_b = (const float*)d_in[6];
    const float* w1 = (const float*)d_in[7];
    const float* b1 = (const float*)d_in[8];
    const float* w2 = (const float*)d_in[9];
    const float* b2 = (const float*)d_in[10];
    const float* w3 = (const float*)d_in[11];
    const float* b3 = (const float*)d_in[12];
    const float* wih = (const float*)d_in[13];
    // d_in[14] = gru_whh: unused (h_old provably zero for every updated node)
    const float* bih = (const float*)d_in[15];
    const float* bhh = (const float*)d_in[16];
    float* out = (float*)d_out;
    char* ws = (char*)d_ws;

    int*   ncnt    = (int*)(ws + OFF_NCNT);
    int*   ecnt    = (int*)(ws + OFF_ECNT);
    float* hs_type = (float*)(ws + OFF_HSTYPE);
    float* hsW1    = (float*)(ws + OFF_HSW1);
    unsigned short* wbmlp = (unsigned short*)(ws + OFF_WBMLP);
    unsigned short* wbih  = (unsigned short*)(ws + OFF_WBIH);
    int*   nlist   = (int*)(ws + OFF_NLIST);
    int*   nslot   = (int*)(ws + OFF_NSLOT);
    int*   esrc    = (int*)(ws + OFF_ESRC);
    int*   edsl    = (int*)(ws + OFF_EDSL);
    float* msg     = (float*)(ws + OFF_MSG);

    hipMemsetAsync(d_ws, 0, WS_USED, stream);

    precompute_kernel<<<1, 256, 0, stream>>>(Ws, Wt, hs_W, hs_b, w1, hs_type, hsW1);
    swizzle_weights<<<(2 * 3 * 49152 + 255) / 256, 256, 0, stream>>>(w1, w2, w3, wih, wbmlp, wbih);
    scatter_hs<<<(NN * 32) / 256, 256, 0, stream>>>(gate, hs_type, out);
    group_nodes<<<(NN + GBS - 1) / GBS, GBS, 0, stream>>>(gate, lvl, ncnt, nlist, nslot);
    group_edges<<<(NE + GBS - 1) / GBS, GBS, 0, stream>>>(gate, lvl, ei, nslot, ecnt, esrc, edsl);

    const float* hf = out + (size_t)NN * HD;
    for (int l = 1; l < 8; l++) {
        msg_kernel<<<3 * 128, 256, 0, stream>>>(l, gate, hf, wbmlp, b1, b2, b3,
                                                hsW1, ecnt, esrc, edsl, msg);
        gru_kernel<<<3 * 64, 256, 0, stream>>>(l, ncnt, nlist, wbih, bih, bhh, msg, out);
    }
}